// Round 3
// baseline (247.605 us; speedup 1.0000x reference)
//
#include <hip/hip_runtime.h>
#include <math.h>
#include <stdint.h>

typedef _Float16 half8 __attribute__((ext_vector_type(8)));
typedef float floatx4 __attribute__((ext_vector_type(4)));

#define NTOK 16384
#define DIM  2048
#define NEXP 64
#define TPB  32                    // tokens per block
#define NBLK (NTOK / TPB)          // 512 blocks
#define KSPL 4                     // K-split across waves
#define KW   (DIM / KSPL)          // 512 k per wave
#define NST  (KW / 32)             // 16 MFMA k-steps per wave
#define RSTR 68                    // 64 + 4 pad -> 2-way bank aliasing only (free)
#define REDF (KSPL * TPB * RSTR)   // 34816 B LDS

// split fp32 -> f16 hi + scaled lo (2^11). hi/lo MFMA triple recovers ~fp32 logits.
__device__ __forceinline__ void split8(const float4& v0, const float4& v1,
                                       half8& hi, half8& lo) {
    const float av[8] = {v0.x, v0.y, v0.z, v0.w, v1.x, v1.y, v1.z, v1.w};
#pragma unroll
    for (int j = 0; j < 8; j++) {
        const _Float16 hh = (_Float16)av[j];
        hi[j] = hh;
        lo[j] = (_Float16)((av[j] - (float)hh) * 2048.0f);
    }
}

// 8 waves/block: wave = (ks, mh). ks = K-slice (512 k), mh = 16-token m-half.
// Each wave: 16 tokens x 64 experts x 512 k, acc in 8 floatx4 (32 AGPR).
// A: register pipeline distance 2 (3 slots, static idx). B: in-step loads (L2-hot).
// launch_bounds(512,4): 4 waves/EU -> 2 blocks/CU -> 16 waves/CU (2x round-2 TLP),
// VGPR cap 128 -> no spill at ~126 live regs.
__global__ __launch_bounds__(512, 4)
void gating_kernel(const float* __restrict__ x, const float* __restrict__ W,
                   const float* __restrict__ bias, float* __restrict__ out)
{
    __shared__ float red[REDF];
    __shared__ float bsh[NEXP];

    const int tid  = threadIdx.x;
    const int lane = tid & 63;
    const int wid  = tid >> 6;          // 0..7
    const int ks   = wid & 3;           // K-split index
    const int mh   = wid >> 2;          // m-half (16 tokens)
    const int col  = lane & 15;
    const int quad = lane >> 4;
    const int tok0 = blockIdx.x * TPB;
    const int k0   = ks * KW;

    if (tid < NEXP) bsh[tid] = bias[tid];

    const float* pA = x + (size_t)(tok0 + mh * 16 + col) * DIM + k0 + quad * 8;
    const float* pB[4];
#pragma unroll
    for (int t = 0; t < 4; t++)
        pB[t] = W + (size_t)(t * 16 + col) * DIM + k0 + quad * 8;

    float4 Ab[3][2];      // [slot][half] — prefetch distance 2
    floatx4 accm[4], accl[4];
#pragma unroll
    for (int t = 0; t < 4; t++) { accm[t] = (floatx4){0,0,0,0}; accl[t] = (floatx4){0,0,0,0}; }

    // prologue: A steps 0,1
#pragma unroll
    for (int s = 0; s < 2; s++)
#pragma unroll
        for (int h = 0; h < 2; h++)
            Ab[s][h] = *(const float4*)(pA + s * 32 + h * 4);

#pragma unroll
    for (int s = 0; s < NST; s++) {
        // issue next-next A (HBM) and this step's B (L2) first: max latency overlap
        if (s + 2 < NST) {
#pragma unroll
            for (int h = 0; h < 2; h++)
                Ab[(s + 2) % 3][h] = *(const float4*)(pA + (s + 2) * 32 + h * 4);
        }
        float4 Bb[4][2];
#pragma unroll
        for (int t = 0; t < 4; t++)
#pragma unroll
            for (int h = 0; h < 2; h++)
                Bb[t][h] = *(const float4*)(pB[t] + s * 32 + h * 4);

        half8 ah, al;
        split8(Ab[s % 3][0], Ab[s % 3][1], ah, al);
#pragma unroll
        for (int t = 0; t < 4; t++) {
            half8 bh, bl;
            split8(Bb[t][0], Bb[t][1], bh, bl);
            accm[t] = __builtin_amdgcn_mfma_f32_16x16x32_f16(ah, bh, accm[t], 0, 0, 0);
            accl[t] = __builtin_amdgcn_mfma_f32_16x16x32_f16(ah, bl, accl[t], 0, 0, 0);
            accl[t] = __builtin_amdgcn_mfma_f32_16x16x32_f16(al, bh, accl[t], 0, 0, 0);
        }
    }

    // K-split partials: wave (ks,mh) writes its [16 tok][64 exp] slab.
    // C/D layout: row = quad*4 + r (token), col = lane&15 (expert) [m89-verified]
    const float inv = 1.0f / 2048.0f;
#pragma unroll
    for (int t = 0; t < 4; t++)
#pragma unroll
        for (int r = 0; r < 4; r++)
            red[(ks * TPB + mh * 16 + quad * 4 + r) * RSTR + t * 16 + col] =
                accm[t][r] + accl[t][r] * inv;
    __syncthreads();

    if (tid < TPB) {
        const int tk = tid;
        float v0 = -INFINITY, v1 = -INFINITY;
        int   i0 = 0, i1 = 0;
        for (int e = 0; e < NEXP; e++) {
            const float v = red[(0 * TPB + tk) * RSTR + e]
                          + red[(1 * TPB + tk) * RSTR + e]
                          + red[(2 * TPB + tk) * RSTR + e]
                          + red[(3 * TPB + tk) * RSTR + e] + bsh[e];
            if (v > v0)      { v1 = v0; i1 = i0; v0 = v; i0 = e; }
            else if (v > v1) { v1 = v; i1 = e; }
        }
        const float e1 = expf(v1 - v0);   // v1 <= v0: stable
        const float sden = 1.f + e1;
        const int   g  = tok0 + tk;
        out[2 * g + 0] = 1.f / sden;
        out[2 * g + 1] = e1 / sden;
        out[2 * NTOK + 2 * g + 0] = (float)i0;
        out[2 * NTOK + 2 * g + 1] = (float)i1;
    }
}

extern "C" void kernel_launch(void* const* d_in, const int* in_sizes, int n_in,
                              void* d_out, int out_size, void* d_ws, size_t ws_size,
                              hipStream_t stream) {
    (void)d_ws; (void)ws_size;
    const float* x    = (const float*)d_in[0];
    const float* W    = (const float*)d_in[1];
    const float* bias = (const float*)d_in[2];
    float*       out  = (float*)d_out;
    hipLaunchKernelGGL(gating_kernel, dim3(NBLK), dim3(512), 0, stream,
                       x, W, bias, out);
}

// Round 6
// 208.554 us; speedup vs baseline: 1.1872x; 1.1872x over previous
//
#include <hip/hip_runtime.h>
#include <math.h>
#include <stdint.h>

typedef _Float16 half8 __attribute__((ext_vector_type(8)));
typedef float floatx4 __attribute__((ext_vector_type(4)));

#define NTOK   16384
#define DIM    2048
#define NEXP   64
#define MB     32                  // tokens per block
#define NBLK   (NTOK / MB)         // 512 blocks
#define KC     64                  // K per chunk
#define NCHUNK (DIM / KC)          // 32
#define WSW_H8 16384               // half8 slots per split (64 ksteps x 4 tg x 64 lanes)
#define WSW_BYTES (2 * WSW_H8 * 16)

#define A_BYTES 8192               // per ring slot: 32 rows x 256 B
#define B_BYTES 16384              // per ring slot: 2 splits x 8 KB
#define AOFF(b) ((b) * A_BYTES)
#define BOFF(b) (3 * A_BYTES + (b) * B_BYTES)
#define SMEM_BYTES (3 * A_BYTES + 3 * B_BYTES)   // 73728 -> 2 blocks/CU

// ---- prep: split W (fp32) into f16 hi + scaled-lo (2^11), B-fragment order:
// slot(sg,tg,lane) = (sg*4+tg)*64+lane holds W[tg*16+(lane&15)][sg*32+(lane>>4)*8 + 0..7]
__global__ void wprep_kernel(const float* __restrict__ W, _Float16* __restrict__ wsw) {
    const int id   = blockIdx.x * blockDim.x + threadIdx.x; // 0..16383
    const int lane = id & 63;
    const int tg   = (id >> 6) & 3;
    const int sg   = id >> 8;                               // 0..63
    const int e    = tg * 16 + (lane & 15);
    const int k    = sg * 32 + (lane >> 4) * 8;
    const float* src = W + (size_t)e * DIM + k;
    half8 h, l;
#pragma unroll
    for (int j = 0; j < 8; j++) {
        const float v  = src[j];
        const _Float16 hh = (_Float16)v;
        h[j] = hh;
        l[j] = (_Float16)((v - (float)hh) * 2048.0f);
    }
    const size_t slot = (size_t)(sg * 4 + tg) * 64 + lane;
    ((half8*)wsw)[slot]          = h;
    ((half8*)wsw)[WSW_H8 + slot] = l;
}

__device__ __forceinline__ void split_a(const float4& v0, const float4& v1,
                                        half8& hi, half8& lo) {
    const float av[8] = {v0.x, v0.y, v0.z, v0.w, v1.x, v1.y, v1.z, v1.w};
#pragma unroll
    for (int j = 0; j < 8; j++) {
        const _Float16 hh = (_Float16)av[j];
        hi[j] = hh;
        lo[j] = (_Float16)((av[j] - (float)hh) * 2048.0f);
    }
}

// async global->LDS DMA, 16 B/lane. LDS dest = WAVE-UNIFORM base (HW appends lane*16).
__device__ __forceinline__ void dma16(const void* g, const char* l) {
    __builtin_amdgcn_global_load_lds(
        (const __attribute__((address_space(1))) unsigned int*)(uintptr_t)g,
        (__attribute__((address_space(3))) unsigned int*)(uintptr_t)l,
        16, 0, 0);
}

template <int N>
__device__ __forceinline__ void wait_vm() {
    asm volatile("s_waitcnt vmcnt(%0)" :: "n"(N) : "memory");
}

// Ring-3 pipeline, ONE barrier per chunk, counted vmcnt (never 0 in the loop).
// Per-wave chronology, iter c (bundle = OPW DMA ops: 2 A + 4 B):
//   1. s_waitcnt vmcnt(OPW)  -> own bundle(c) landed (only bundle(c+1) still in
//      flight; bundle(c+2) NOT yet issued)
//   2. s_barrier             -> ALL waves' bundle(c) landed; chunk c fully staged.
//      Also: all waves finished compute(c-1), so slot (c-1)%3 reads are done.
//   3. issue bundle(c+2) into slot (c+2)%3 == (c-1)%3   [race-free ONLY here,
//      after the barrier — R4's issue-before-barrier clobbered slow waves' reads]
//   4. ds_read frags from slot c%3, compute (compiler emits its own lgkmcnt)
// Issue-to-use distance = 2 chunk-times (~>900 cyc HBM latency covered).
template <bool USE_WS>
__global__ __launch_bounds__(256, 2)
void gating_lds_kernel(const float* __restrict__ x, const float* __restrict__ W,
                       const _Float16* __restrict__ wsw, const float* __restrict__ bias,
                       float* __restrict__ out)
{
    __shared__ char smem[SMEM_BYTES];

    const int tid  = threadIdx.x;
    const int lane = tid & 63;
    const int w    = tid >> 6;          // 0..3
    const int mt   = w & 1;             // m-tile (16 tokens)
    const int nh   = w >> 1;            // n-half (2 expert tiles)
    const int col  = lane & 15;
    const int quad = lane >> 4;
    const int tok0 = blockIdx.x * MB;
    const int m    = mt * 16 + col;     // this lane's token row (0..31)

    // ---- A DMA sources: issue a = w*2+i covers rows a*4..a*4+3 (256 B each).
    // Gather-side XOR swizzle within 128 B: LDS slot pz holds global piece
    // (pz&8)|((pz&7)^(row&7))  => frag ds_reads land on distinct banks.
    const float* gA[2];
    unsigned     lA[2];
#pragma unroll
    for (int i = 0; i < 2; i++) {
        const int a   = w * 2 + i;
        const int row = a * 4 + (lane >> 4);
        const int pz  = lane & 15;
        const int gp  = (pz & 8) | ((pz & 7) ^ (row & 7));
        gA[i] = x + (size_t)(tok0 + row) * DIM + gp * 4;
        lA[i] = (unsigned)(a * 1024);
    }
    // ---- B DMA sources: contiguous copy of wsw chunk (lane-contiguous LDS).
    const half8* gB[4];
    unsigned     lB[4];
    if constexpr (USE_WS) {
#pragma unroll
        for (int j = 0; j < 4; j++) {
            const int b = w * 4 + j;
            const int split = b >> 3, idx = b & 7;
            gB[j] = (const half8*)wsw + (size_t)split * WSW_H8 + idx * 64 + lane;
            lB[j] = (unsigned)(split * 8192 + idx * 1024);
        }
    }
    constexpr int OPW = USE_WS ? 6 : 2;   // own DMA ops per bundle

    floatx4 accm[2] = {{0,0,0,0},{0,0,0,0}};
    floatx4 accl[2] = {{0,0,0,0},{0,0,0,0}};

    // prologue: bundles 0 and 1 into slots 0,1
#pragma unroll
    for (int c0 = 0; c0 < 2; c0++) {
#pragma unroll
        for (int i = 0; i < 2; i++)
            dma16(gA[i] + (size_t)c0 * KC, smem + AOFF(c0) + lA[i]);
        if constexpr (USE_WS) {
#pragma unroll
            for (int j = 0; j < 4; j++)
                dma16(gB[j] + (size_t)c0 * 512, smem + BOFF(c0) + lB[j]);
        }
    }

    int bi = 0, pi = 2;   // read slot (c%3), prefetch slot ((c+2)%3)
    for (int c = 0; c < NCHUNK; ++c) {
        if (c < NCHUNK - 1) wait_vm<OPW>();
        else                wait_vm<0>();
        __builtin_amdgcn_s_barrier();
        asm volatile("" ::: "memory");   // no mem op crosses the barrier

        if (c + 2 < NCHUNK) {            // safe ONLY after the barrier (see header)
#pragma unroll
            for (int i = 0; i < 2; i++)
                dma16(gA[i] + (size_t)(c + 2) * KC, smem + AOFF(pi) + lA[i]);
            if constexpr (USE_WS) {
#pragma unroll
                for (int j = 0; j < 4; j++)
                    dma16(gB[j] + (size_t)(c + 2) * 512, smem + BOFF(pi) + lB[j]);
            }
        }

        const char* Ab = smem + AOFF(bi);
        const char* Bb = smem + BOFF(bi);
#pragma unroll
        for (int s = 0; s < 2; s++) {
            const float4 v0 = *(const float4*)(Ab + m * 256 + (8 * s + ((2 * quad + 0) ^ (m & 7))) * 16);
            const float4 v1 = *(const float4*)(Ab + m * 256 + (8 * s + ((2 * quad + 1) ^ (m & 7))) * 16);
            half8 ah, alo;
            split_a(v0, v1, ah, alo);
#pragma unroll
            for (int t = 0; t < 2; t++) {
                const int tg = nh * 2 + t;
                half8 bh, bl;
                if constexpr (USE_WS) {
                    bh = *(const half8*)(Bb + (s * 4 + tg) * 1024 + lane * 16);
                    bl = *(const half8*)(Bb + 8192 + (s * 4 + tg) * 1024 + lane * 16);
                } else {
                    const float* wr = W + (size_t)(tg * 16 + col) * DIM + c * KC + s * 32 + quad * 8;
                    split_a(*(const float4*)wr, *(const float4*)(wr + 4), bh, bl);
                }
                accm[t] = __builtin_amdgcn_mfma_f32_16x16x32_f16(ah,  bh, accm[t], 0, 0, 0);
                accl[t] = __builtin_amdgcn_mfma_f32_16x16x32_f16(ah,  bl, accl[t], 0, 0, 0);
                accl[t] = __builtin_amdgcn_mfma_f32_16x16x32_f16(alo, bh, accl[t], 0, 0, 0);
            }
        }
        bi = (bi == 2) ? 0 : bi + 1;
        pi = (pi == 2) ? 0 : pi + 1;
    }

    __syncthreads();            // loop done (vmcnt fully drained by last wait). Alias logits on A region.
    float* lg = (float*)smem;   // [32 tok][65] stride-65
    const float inv = 1.0f / 2048.0f;
#pragma unroll
    for (int t = 0; t < 2; t++) {
        const int tg = nh * 2 + t;
#pragma unroll
        for (int r = 0; r < 4; r++) {
            // C/D: row = quad*4+r, col = lane&15  [m89-verified]
            lg[(mt * 16 + quad * 4 + r) * 65 + tg * 16 + col] = accm[t][r] + accl[t][r] * inv;
        }
    }
    __syncthreads();

    if (tid < MB) {
        const int t = tid;
        float v0 = -INFINITY, v1 = -INFINITY;
        int   i0 = 0, i1 = 0;
        for (int e = 0; e < NEXP; e++) {
            const float v = lg[t * 65 + e] + bias[e];
            if (v > v0) { v1 = v0; i1 = i0; v0 = v; i0 = e; }
            else if (v > v1) { v1 = v; i1 = e; }
        }
        const float e1 = expf(v1 - v0);   // v1 <= v0: stable
        const float sden = 1.f + e1;
        const int   g  = tok0 + t;
        out[2 * g + 0] = 1.f / sden;
        out[2 * g + 1] = e1 / sden;
        out[2 * NTOK + 2 * g + 0] = (float)i0;
        out[2 * NTOK + 2 * g + 1] = (float)i1;
    }
}

extern "C" void kernel_launch(void* const* d_in, const int* in_sizes, int n_in,
                              void* d_out, int out_size, void* d_ws, size_t ws_size,
                              hipStream_t stream) {
    const float* x    = (const float*)d_in[0];
    const float* W    = (const float*)d_in[1];
    const float* bias = (const float*)d_in[2];
    float*       out  = (float*)d_out;
    _Float16*    wsw  = (_Float16*)d_ws;

    if (ws_size >= (size_t)WSW_BYTES) {
        hipLaunchKernelGGL(wprep_kernel, dim3(64), dim3(256), 0, stream, W, wsw);
        hipLaunchKernelGGL((gating_lds_kernel<true>), dim3(NBLK), dim3(256), 0, stream,
                           x, W, wsw, bias, out);
    } else {
        hipLaunchKernelGGL((gating_lds_kernel<false>), dim3(NBLK), dim3(256), 0, stream,
                           x, W, wsw, bias, out);
    }
}